// Round 18
// baseline (179.991 us; speedup 1.0000x reference)
//
#include <hip/hip_runtime.h>
#include <hip/hip_bf16.h>

#define IN_DIM  128
#define OUT_DIM 64
#define EPB 4096          // edges per count/partition block
#define NBK_MAX 512       // max coarse buckets (n <= 131072)

typedef short  bf16x8 __attribute__((ext_vector_type(8)));
typedef float  f32x4  __attribute__((ext_vector_type(4)));

__device__ __forceinline__ unsigned short f2bf(float f) {   // RNE
    unsigned u = __float_as_uint(f);
    u += 0x7fffu + ((u >> 16) & 1u);
    return (unsigned short)(u >> 16);
}
__device__ __forceinline__ float bf2f(unsigned short h) {
    return __uint_as_float((unsigned)h << 16);
}

// ---------------------------------------------------------------------------
// CSR build, two-level LDS counting sort (no global atomics). R14-proven.
// Bucket = dst >> 8. Record = (dst&255)<<17 | src (u32, src < 2^17).
// ---------------------------------------------------------------------------
__global__ __launch_bounds__(256) void k_cnt(const int* __restrict__ dst,
                                             unsigned* __restrict__ colcnt,
                                             int nE, int nbk, int nblk) {
    __shared__ unsigned h[NBK_MAX];
    for (int b = threadIdx.x; b < NBK_MAX; b += 256) h[b] = 0u;
    __syncthreads();
    int blk = blockIdx.x;
    int e0 = blk * EPB, e1 = min(e0 + EPB, nE);
    for (int e = e0 + threadIdx.x; e < e1; e += 256)
        atomicAdd(&h[dst[e] >> 8], 1u);
    __syncthreads();
    for (int b = threadIdx.x; b < nbk; b += 256)
        colcnt[(size_t)b * nblk + blk] = h[b];
}

__global__ __launch_bounds__(512) void k_bsum(unsigned* __restrict__ colcnt,
                                              unsigned* __restrict__ btot,
                                              int nbk, int nblk) {
    __shared__ unsigned s[512];
    int b = blockIdx.x;
    unsigned v = (threadIdx.x < (unsigned)nblk) ? colcnt[(size_t)b * nblk + threadIdx.x] : 0u;
    s[threadIdx.x] = v;
    __syncthreads();
    for (int d = 1; d < 512; d <<= 1) {
        unsigned t = (threadIdx.x >= (unsigned)d) ? s[threadIdx.x - d] : 0u;
        __syncthreads();
        s[threadIdx.x] += t;
        __syncthreads();
    }
    if (threadIdx.x < (unsigned)nblk)
        colcnt[(size_t)b * nblk + threadIdx.x] = s[threadIdx.x] - v;
    if (threadIdx.x == 511) btot[b] = s[511];
}

__global__ __launch_bounds__(512) void k_btots(const unsigned* __restrict__ btot,
                                               unsigned* __restrict__ bbase,
                                               int nbk, int nE) {
    __shared__ unsigned s[512];
    unsigned v = (threadIdx.x < (unsigned)nbk) ? btot[threadIdx.x] : 0u;
    s[threadIdx.x] = v;
    __syncthreads();
    for (int d = 1; d < 512; d <<= 1) {
        unsigned t = (threadIdx.x >= (unsigned)d) ? s[threadIdx.x - d] : 0u;
        __syncthreads();
        s[threadIdx.x] += t;
        __syncthreads();
    }
    if (threadIdx.x < (unsigned)nbk) bbase[threadIdx.x] = s[threadIdx.x] - v;
    if (threadIdx.x == 0) bbase[nbk] = (unsigned)nE;
}

__global__ __launch_bounds__(256) void k_part(const int* __restrict__ src,
                                              const int* __restrict__ dst,
                                              const unsigned* __restrict__ colcnt,
                                              const unsigned* __restrict__ bbase,
                                              unsigned* __restrict__ ebuf,
                                              int nE, int nbk, int nblk) {
    __shared__ unsigned curs[NBK_MAX];
    int blk = blockIdx.x;
    for (int b = threadIdx.x; b < nbk; b += 256)
        curs[b] = bbase[b] + colcnt[(size_t)b * nblk + blk];
    __syncthreads();
    int e0 = blk * EPB, e1 = min(e0 + EPB, nE);
    for (int e = e0 + threadIdx.x; e < e1; e += 256) {
        int d = dst[e], s = src[e];
        unsigned p = atomicAdd(&curs[d >> 8], 1u);
        ebuf[p] = ((unsigned)(d & 255) << 17) | (unsigned)s;
    }
}

__global__ __launch_bounds__(256) void k_fine(const unsigned* __restrict__ ebuf,
                                              const unsigned* __restrict__ bbase,
                                              unsigned* __restrict__ offs,
                                              float* __restrict__ dinv,
                                              int* __restrict__ perm, int n) {
    __shared__ unsigned deg[256], pos[256], cur[256];
    int b = blockIdx.x;
    int node0 = b << 8;
    unsigned ebeg = bbase[b], eend = bbase[b + 1];
    deg[threadIdx.x] = 0u;
    __syncthreads();
    for (unsigned e = ebeg + threadIdx.x; e < eend; e += 256)
        atomicAdd(&deg[ebuf[e] >> 17], 1u);
    __syncthreads();
    unsigned v = deg[threadIdx.x];
    pos[threadIdx.x] = v;
    __syncthreads();
    for (int d = 1; d < 256; d <<= 1) {
        unsigned t = (threadIdx.x >= (unsigned)d) ? pos[threadIdx.x - d] : 0u;
        __syncthreads();
        pos[threadIdx.x] += t;
        __syncthreads();
    }
    unsigned excl = pos[threadIdx.x] - v;
    cur[threadIdx.x] = excl;
    int node = node0 + threadIdx.x;
    if (node < n) {
        offs[node] = ebeg + excl;
        dinv[node] = rsqrtf((float)v + 1.0f);    // +1 self-loop
    }
    __syncthreads();
    for (unsigned e = ebeg + threadIdx.x; e < eend; e += 256) {
        unsigned rec = ebuf[e];
        unsigned p = atomicAdd(&cur[rec >> 17], 1u);
        perm[ebeg + p] = (int)(rec & 0x1FFFFu);
    }
}

// ---------------------------------------------------------------------------
// MFMA linear layer 1 (R13-proven): hs[r] = bf16(dinv[r]*(x[r] @ W1)).
// bf16 hi/lo split (hh+hl+lh), 64 rows/block, W->LDS transposed+padded.
// ---------------------------------------------------------------------------
template <int KD>
__global__ __launch_bounds__(256) void k_linm(const float* __restrict__ in,
                                              const float* __restrict__ W,   // [KD][64]
                                              const float* __restrict__ dinv,
                                              unsigned short* __restrict__ outp, int n) {
    constexpr int LDK = KD + 8;
    __shared__ unsigned short WH[64 * LDK];
    __shared__ unsigned short WL[64 * LDK];
    for (int i = threadIdx.x; i < KD * 64; i += 256) {
        int k = i >> 6, c = i & 63;
        float wv = W[i];
        unsigned short h = f2bf(wv);
        WH[c * LDK + k] = h;
        WL[c * LDK + k] = f2bf(wv - bf2f(h));
    }
    __syncthreads();

    int wid = threadIdx.x >> 6, lane = threadIdx.x & 63;
    int r0 = blockIdx.x * 64 + wid * 16;

    constexpr int NK = KD / 32;
    int arow = r0 + (lane & 15);
    int ar = arow < n ? arow : (n - 1);
    int k8 = (lane >> 4) * 8;

    bf16x8 ah[NK], al[NK];
    {
        const float* rp = in + (size_t)ar * KD;
#pragma unroll
        for (int ks = 0; ks < NK; ++ks) {
            float4 v0 = *(const float4*)(rp + ks * 32 + k8);
            float4 v1 = *(const float4*)(rp + ks * 32 + k8 + 4);
            float xv[8] = {v0.x, v0.y, v0.z, v0.w, v1.x, v1.y, v1.z, v1.w};
#pragma unroll
            for (int j = 0; j < 8; ++j) {
                float f = xv[j];
                unsigned short h = f2bf(f);
                ah[ks][j] = (short)h;
                al[ks][j] = (short)f2bf(f - bf2f(h));
            }
        }
    }

    f32x4 acc[4];
#pragma unroll
    for (int nt = 0; nt < 4; ++nt) {
        int col = nt * 16 + (lane & 15);
        const unsigned short* bh = &WH[col * LDK + k8];
        const unsigned short* bl = &WL[col * LDK + k8];
        f32x4 a = {0.f, 0.f, 0.f, 0.f};
#pragma unroll
        for (int ks = 0; ks < NK; ++ks) {
            bf16x8 Bh = *(const bf16x8*)(bh + ks * 32);
            bf16x8 Bl = *(const bf16x8*)(bl + ks * 32);
            a = __builtin_amdgcn_mfma_f32_16x16x32_bf16(ah[ks], Bh, a, 0, 0, 0);
            a = __builtin_amdgcn_mfma_f32_16x16x32_bf16(ah[ks], Bl, a, 0, 0, 0);
            a = __builtin_amdgcn_mfma_f32_16x16x32_bf16(al[ks], Bh, a, 0, 0, 0);
        }
        acc[nt] = a;
    }

    int orow0 = r0 + (lane >> 4) * 4;
#pragma unroll
    for (int j = 0; j < 4; ++j) {
        int row = orow0 + j;
        if (row < n) {
            float dv = dinv[row];
#pragma unroll
            for (int nt = 0; nt < 4; ++nt)
                outp[(size_t)row * 64 + nt * 16 + (lane & 15)] = f2bf(dv * acc[nt][j]);
        }
    }
}

// ---------------------------------------------------------------------------
// FUSED gather1 + linm2: R17's dual-node gather accumulates agg rows in
// registers; epilogue applies relu(dinv*agg), hi/lo-splits to bf16 and stages
// the 32-row A-tile in LDS; after syncthreads, 4 waves run the 3-term MFMA
// against W2 (hi/lo in LDS) and store hs2 = bf16(dinv*(h1@W2)) directly.
// The 25MB f32 agg buffer never exists (50MB traffic + 1 dispatch removed).
// ---------------------------------------------------------------------------
__global__ __launch_bounds__(256) void k_gl(const unsigned short* __restrict__ hs,
                                            const unsigned* __restrict__ offs,
                                            const int* __restrict__ perm,
                                            const float* __restrict__ dinv,
                                            const float* __restrict__ W2,    // [64][64]
                                            unsigned short* __restrict__ hs2,
                                            int n, int nE) {
    constexpr int LDK = 72;                       // pad (16B-aligned rows)
    __shared__ unsigned short WH[64 * LDK];       // 9.2 KB
    __shared__ unsigned short WL[64 * LDK];       // 9.2 KB
    __shared__ unsigned short AH[32 * LDK];       // 4.6 KB
    __shared__ unsigned short AL[32 * LDK];       // 4.6 KB

    // stage W2 (transposed, hi/lo)
    for (int i = threadIdx.x; i < 64 * 64; i += 256) {
        int k = i >> 6, c = i & 63;
        float wv = W2[i];
        unsigned short h = f2bf(wv);
        WH[c * LDK + k] = h;
        WL[c * LDK + k] = f2bf(wv - bf2f(h));
    }

    int lane = threadIdx.x & 63;
    int wv_ = threadIdx.x >> 6;                   // wave id 0..3
    int g = lane >> 4, li = lane & 15;
    int base = blockIdx.x * 32;
    int lA = wv_ * 8 + g, lB = lA + 4;            // local rows 0..31
    int rA = base + lA, rB = base + lB;
    bool vA = rA < n, vB = rB < n;
    int rcA = vA ? rA : (n - 1);
    int rcB = vB ? rB : (n - 1);
    unsigned begA = offs[rcA];
    unsigned endA = (rcA + 1 < n) ? offs[rcA + 1] : (unsigned)nE;
    unsigned begB = offs[rcB];
    unsigned endB = (rcB + 1 < n) ? offs[rcB + 1] : (unsigned)nE;
    unsigned degA = vA ? (endA - begA) : 0u;
    unsigned degB = vB ? (endB - begB) : 0u;

    // self-loop terms
    float4 qA0, qA1 = {0.f,0.f,0.f,0.f}, qA2 = qA1, qA3 = qA1;
    float4 qB0, qB1 = qA1, qB2 = qA1, qB3 = qA1;
    {
        ushort4 sv = *(const ushort4*)(hs + (size_t)rcA * 64 + li * 4);
        qA0.x = bf2f(sv.x); qA0.y = bf2f(sv.y); qA0.z = bf2f(sv.z); qA0.w = bf2f(sv.w);
        ushort4 tv = *(const ushort4*)(hs + (size_t)rcB * 64 + li * 4);
        qB0.x = bf2f(tv.x); qB0.y = bf2f(tv.y); qB0.z = bf2f(tv.z); qB0.w = bf2f(tv.w);
    }

    unsigned dm = max(degA, degB);
    dm = max(dm, (unsigned)__shfl_xor((int)dm, 16));
    dm = max(dm, (unsigned)__shfl_xor((int)dm, 32));

    int slA = (li < (int)degA) ? perm[begA + li] : 0;
    int slB = (li < (int)degB) ? perm[begB + li] : 0;

    for (unsigned c0 = 0; c0 < dm; c0 += 16) {
        int sAc = slA, sBc = slB;
        unsigned c1 = c0 + 16;
        if (c1 < dm) {
            slA = (c1 + li < degA) ? perm[begA + c1 + li] : 0;
            slB = (c1 + li < degB) ? perm[begB + c1 + li] : 0;
        }
#pragma unroll
        for (int k = 0; k < 16; ++k) {
            int sA = __shfl(sAc, g * 16 + k);
            int sB = __shfl(sBc, g * 16 + k);
            if (c0 + k < degA) {
                ushort4 v = *(const ushort4*)(hs + (size_t)sA * 64 + li * 4);
                float4* q = (k & 2) ? ((k & 1) ? &qA3 : &qA2) : ((k & 1) ? &qA1 : &qA0);
                q->x += bf2f(v.x); q->y += bf2f(v.y); q->z += bf2f(v.z); q->w += bf2f(v.w);
            }
            if (c0 + k < degB) {
                ushort4 v = *(const ushort4*)(hs + (size_t)sB * 64 + li * 4);
                float4* q = (k & 2) ? ((k & 1) ? &qB3 : &qB2) : ((k & 1) ? &qB1 : &qB0);
                q->x += bf2f(v.x); q->y += bf2f(v.y); q->z += bf2f(v.z); q->w += bf2f(v.w);
            }
        }
    }

    // epilogue: h1 = relu(dinv*agg); hi/lo split -> LDS A-tile
    {
        float dvA = dinv[rcA], dvB = dinv[rcB];
        float4 aA, aB;
        aA.x = (qA0.x + qA1.x) + (qA2.x + qA3.x);
        aA.y = (qA0.y + qA1.y) + (qA2.y + qA3.y);
        aA.z = (qA0.z + qA1.z) + (qA2.z + qA3.z);
        aA.w = (qA0.w + qA1.w) + (qA2.w + qA3.w);
        aB.x = (qB0.x + qB1.x) + (qB2.x + qB3.x);
        aB.y = (qB0.y + qB1.y) + (qB2.y + qB3.y);
        aB.z = (qB0.z + qB1.z) + (qB2.z + qB3.z);
        aB.w = (qB0.w + qB1.w) + (qB2.w + qB3.w);
        float fA[4] = {fmaxf(dvA * aA.x, 0.f), fmaxf(dvA * aA.y, 0.f),
                       fmaxf(dvA * aA.z, 0.f), fmaxf(dvA * aA.w, 0.f)};
        float fB[4] = {fmaxf(dvB * aB.x, 0.f), fmaxf(dvB * aB.y, 0.f),
                       fmaxf(dvB * aB.z, 0.f), fmaxf(dvB * aB.w, 0.f)};
        ushort4 hA, lA4, hB, lB4;
        hA.x = f2bf(fA[0]); lA4.x = f2bf(fA[0] - bf2f(hA.x));
        hA.y = f2bf(fA[1]); lA4.y = f2bf(fA[1] - bf2f(hA.y));
        hA.z = f2bf(fA[2]); lA4.z = f2bf(fA[2] - bf2f(hA.z));
        hA.w = f2bf(fA[3]); lA4.w = f2bf(fA[3] - bf2f(hA.w));
        hB.x = f2bf(fB[0]); lB4.x = f2bf(fB[0] - bf2f(hB.x));
        hB.y = f2bf(fB[1]); lB4.y = f2bf(fB[1] - bf2f(hB.y));
        hB.z = f2bf(fB[2]); lB4.z = f2bf(fB[2] - bf2f(hB.z));
        hB.w = f2bf(fB[3]); lB4.w = f2bf(fB[3] - bf2f(hB.w));
        *(ushort4*)&AH[lA * LDK + li * 4] = hA;
        *(ushort4*)&AL[lA * LDK + li * 4] = lA4;
        *(ushort4*)&AH[lB * LDK + li * 4] = hB;
        *(ushort4*)&AL[lB * LDK + li * 4] = lB4;
    }
    __syncthreads();

    // MFMA phase: wave -> (stripe = wv_>>1, N-tile pair = (wv_&1)*2)
    int stripe = wv_ >> 1;
    int ntb = (wv_ & 1) * 2;
    int arow = stripe * 16 + (lane & 15);
    int k8 = (lane >> 4) * 8;
    bf16x8 ah[2], al[2];
#pragma unroll
    for (int ks = 0; ks < 2; ++ks) {
        ah[ks] = *(const bf16x8*)&AH[arow * LDK + ks * 32 + k8];
        al[ks] = *(const bf16x8*)&AL[arow * LDK + ks * 32 + k8];
    }
#pragma unroll
    for (int t = 0; t < 2; ++t) {
        int nt = ntb + t;
        int col = nt * 16 + (lane & 15);
        const unsigned short* bh = &WH[col * LDK + k8];
        const unsigned short* bl = &WL[col * LDK + k8];
        f32x4 a = {0.f, 0.f, 0.f, 0.f};
#pragma unroll
        for (int ks = 0; ks < 2; ++ks) {
            bf16x8 Bh = *(const bf16x8*)(bh + ks * 32);
            bf16x8 Bl = *(const bf16x8*)(bl + ks * 32);
            a = __builtin_amdgcn_mfma_f32_16x16x32_bf16(ah[ks], Bh, a, 0, 0, 0);
            a = __builtin_amdgcn_mfma_f32_16x16x32_bf16(ah[ks], Bl, a, 0, 0, 0);
            a = __builtin_amdgcn_mfma_f32_16x16x32_bf16(al[ks], Bh, a, 0, 0, 0);
        }
        int orow0 = base + stripe * 16 + (lane >> 4) * 4;
#pragma unroll
        for (int j = 0; j < 4; ++j) {
            int row = orow0 + j;
            if (row < n)
                hs2[(size_t)row * 64 + col] = f2bf(dinv[row] * a[j]);
        }
    }
}

// ---------------------------------------------------------------------------
// CSR gather layer-2 (R17 structure): dual-node per group, deep MLP;
// applies final dinv and writes f32 output.
// ---------------------------------------------------------------------------
__global__ __launch_bounds__(256) void k_gather2(const unsigned short* __restrict__ hs,
                                                 const unsigned* __restrict__ offs,
                                                 const int* __restrict__ perm,
                                                 const float* __restrict__ dinv,
                                                 float* __restrict__ outb,
                                                 int n, int nE) {
    int lane = threadIdx.x & 63;
    int g = lane >> 4, li = lane & 15;
    int base = (blockIdx.x * 4 + (threadIdx.x >> 6)) * 8;
    int rA = base + g;
    int rB = base + 4 + g;
    bool vA = rA < n, vB = rB < n;
    int rcA = vA ? rA : (n - 1);
    int rcB = vB ? rB : (n - 1);
    unsigned begA = offs[rcA];
    unsigned endA = (rcA + 1 < n) ? offs[rcA + 1] : (unsigned)nE;
    unsigned begB = offs[rcB];
    unsigned endB = (rcB + 1 < n) ? offs[rcB + 1] : (unsigned)nE;
    unsigned degA = vA ? (endA - begA) : 0u;
    unsigned degB = vB ? (endB - begB) : 0u;

    float4 qA0, qA1 = {0.f,0.f,0.f,0.f}, qA2 = qA1, qA3 = qA1;
    float4 qB0, qB1 = qA1, qB2 = qA1, qB3 = qA1;
    {
        ushort4 sv = *(const ushort4*)(hs + (size_t)rcA * 64 + li * 4);
        qA0.x = bf2f(sv.x); qA0.y = bf2f(sv.y); qA0.z = bf2f(sv.z); qA0.w = bf2f(sv.w);
        ushort4 tv = *(const ushort4*)(hs + (size_t)rcB * 64 + li * 4);
        qB0.x = bf2f(tv.x); qB0.y = bf2f(tv.y); qB0.z = bf2f(tv.z); qB0.w = bf2f(tv.w);
    }

    unsigned dm = max(degA, degB);
    dm = max(dm, (unsigned)__shfl_xor((int)dm, 16));
    dm = max(dm, (unsigned)__shfl_xor((int)dm, 32));

    int slA = (li < (int)degA) ? perm[begA + li] : 0;
    int slB = (li < (int)degB) ? perm[begB + li] : 0;

    for (unsigned c0 = 0; c0 < dm; c0 += 16) {
        int sAc = slA, sBc = slB;
        unsigned c1 = c0 + 16;
        if (c1 < dm) {
            slA = (c1 + li < degA) ? perm[begA + c1 + li] : 0;
            slB = (c1 + li < degB) ? perm[begB + c1 + li] : 0;
        }
#pragma unroll
        for (int k = 0; k < 16; ++k) {
            int sA = __shfl(sAc, g * 16 + k);
            int sB = __shfl(sBc, g * 16 + k);
            if (c0 + k < degA) {
                ushort4 v = *(const ushort4*)(hs + (size_t)sA * 64 + li * 4);
                float4* q = (k & 2) ? ((k & 1) ? &qA3 : &qA2) : ((k & 1) ? &qA1 : &qA0);
                q->x += bf2f(v.x); q->y += bf2f(v.y); q->z += bf2f(v.z); q->w += bf2f(v.w);
            }
            if (c0 + k < degB) {
                ushort4 v = *(const ushort4*)(hs + (size_t)sB * 64 + li * 4);
                float4* q = (k & 2) ? ((k & 1) ? &qB3 : &qB2) : ((k & 1) ? &qB1 : &qB0);
                q->x += bf2f(v.x); q->y += bf2f(v.y); q->z += bf2f(v.z); q->w += bf2f(v.w);
            }
        }
    }

    if (vA) {
        float4 acc;
        acc.x = (qA0.x + qA1.x) + (qA2.x + qA3.x);
        acc.y = (qA0.y + qA1.y) + (qA2.y + qA3.y);
        acc.z = (qA0.z + qA1.z) + (qA2.z + qA3.z);
        acc.w = (qA0.w + qA1.w) + (qA2.w + qA3.w);
        float dv = dinv[rA];
        acc.x *= dv; acc.y *= dv; acc.z *= dv; acc.w *= dv;
        *(float4*)(outb + (size_t)rA * 64 + li * 4) = acc;
    }
    if (vB) {
        float4 acc;
        acc.x = (qB0.x + qB1.x) + (qB2.x + qB3.x);
        acc.y = (qB0.y + qB1.y) + (qB2.y + qB3.y);
        acc.z = (qB0.z + qB1.z) + (qB2.z + qB3.z);
        acc.w = (qB0.w + qB1.w) + (qB2.w + qB3.w);
        float dv = dinv[rB];
        acc.x *= dv; acc.y *= dv; acc.z *= dv; acc.w *= dv;
        *(float4*)(outb + (size_t)rB * 64 + li * 4) = acc;
    }
}

// ---------------------------------------------------------------------------
extern "C" void kernel_launch(void* const* d_in, const int* in_sizes, int n_in,
                              void* d_out, int out_size, void* d_ws, size_t ws_size,
                              hipStream_t stream) {
    const float* x  = (const float*)d_in[0];
    const int*   ei = (const int*)d_in[1];
    const float* W1 = (const float*)d_in[2];
    const float* W2 = (const float*)d_in[3];
    float* out = (float*)d_out;

    int n  = in_sizes[0] / IN_DIM;   // 100000
    int nE = in_sizes[1] / 2;        // 1600000
    const int* src = ei;
    const int* dst = ei + nE;

    int nbk  = (n + 255) >> 8;               // coarse buckets
    int nblk = (nE + EPB - 1) / EPB;         // count/partition blocks

    // workspace carve-up (256B-aligned)
    char* w = (char*)d_ws;
    size_t nAl = ((size_t)n * 4 + 255) & ~(size_t)255;
    float*          dinv   = (float*)w;     w += nAl;
    unsigned*       offs   = (unsigned*)w;  w += nAl;
    unsigned*       colcnt = (unsigned*)w;  w += ((size_t)nbk * nblk * 4 + 255) & ~(size_t)255;
    unsigned*       btot   = (unsigned*)w;  w += ((size_t)nbk * 4 + 255) & ~(size_t)255;
    unsigned*       bbase  = (unsigned*)w;  w += ((size_t)(nbk + 1) * 4 + 255) & ~(size_t)255;
    unsigned*       ebuf   = (unsigned*)w;  w += ((size_t)nE * 4 + 255) & ~(size_t)255;
    int*            perm   = (int*)w;       w += ((size_t)nE * 4 + 255) & ~(size_t)255;
    unsigned short* hs     = (unsigned short*)w; w += (size_t)n * 64 * 2;
    unsigned short* hs2    = (unsigned short*)w; w += (size_t)n * 64 * 2;

    int gMf  = (n + 63) / 64;
    int gFus = (n + 31) / 32;

    // --- CSR build: two-level LDS counting sort ---
    k_cnt  <<<nblk, 256, 0, stream>>>(dst, colcnt, nE, nbk, nblk);
    k_bsum <<<nbk,  512, 0, stream>>>(colcnt, btot, nbk, nblk);
    k_btots<<<1,    512, 0, stream>>>(btot, bbase, nbk, nE);
    k_part <<<nblk, 256, 0, stream>>>(src, dst, colcnt, bbase, ebuf, nE, nbk, nblk);
    k_fine <<<nbk,  256, 0, stream>>>(ebuf, bbase, offs, dinv, perm, n);

    // --- layer 1 linear ---
    k_linm<IN_DIM><<<gMf, 256, 0, stream>>>(x, W1, dinv, hs, n);

    // --- fused: gather1 + relu/dinv + W2 matmul -> hs2 ---
    k_gl<<<gFus, 256, 0, stream>>>(hs, offs, perm, dinv, W2, hs2, n, nE);

    // --- layer 2 aggregate -> out ---
    k_gather2<<<(n + 31) / 32, 256, 0, stream>>>(hs2, offs, perm, dinv, out, n, nE);
}

// Round 19
// 165.212 us; speedup vs baseline: 1.0894x; 1.0894x over previous
//
#include <hip/hip_runtime.h>
#include <hip/hip_bf16.h>

#define IN_DIM  128
#define OUT_DIM 64
#define EPB 4096          // edges per count/partition block
#define NBK_MAX 512       // max coarse buckets (n <= 131072)

typedef short  bf16x8 __attribute__((ext_vector_type(8)));
typedef float  f32x4  __attribute__((ext_vector_type(4)));
typedef unsigned long long u64;

__device__ __forceinline__ unsigned short f2bf(float f) {   // RNE
    unsigned u = __float_as_uint(f);
    u += 0x7fffu + ((u >> 16) & 1u);
    return (unsigned short)(u >> 16);
}
__device__ __forceinline__ float bf2f(unsigned short h) {
    return __uint_as_float((unsigned)h << 16);
}

// ---------------------------------------------------------------------------
// CSR build, two-level LDS counting sort (no global atomics).
// Bucket = dst >> 8 (256 nodes per bucket).
// ---------------------------------------------------------------------------

// Phase 1: per-block coarse histogram -> colcnt[bucket][blk]
__global__ __launch_bounds__(256) void k_cnt(const int* __restrict__ dst,
                                             unsigned* __restrict__ colcnt,
                                             int nE, int nbk, int nblk) {
    __shared__ unsigned h[NBK_MAX];
    for (int b = threadIdx.x; b < NBK_MAX; b += 256) h[b] = 0u;
    __syncthreads();
    int blk = blockIdx.x;
    int e0 = blk * EPB, e1 = min(e0 + EPB, nE);
    for (int e = e0 + threadIdx.x; e < e1; e += 256)
        atomicAdd(&h[dst[e] >> 8], 1u);
    __syncthreads();
    for (int b = threadIdx.x; b < nbk; b += 256)
        colcnt[(size_t)b * nblk + blk] = h[b];
}

// Phase 2a: per-bucket exclusive scan over blocks (in place); totals out.
__global__ __launch_bounds__(512) void k_bsum(unsigned* __restrict__ colcnt,
                                              unsigned* __restrict__ btot,
                                              int nbk, int nblk) {
    __shared__ unsigned s[512];
    int b = blockIdx.x;
    unsigned v = (threadIdx.x < (unsigned)nblk) ? colcnt[(size_t)b * nblk + threadIdx.x] : 0u;
    s[threadIdx.x] = v;
    __syncthreads();
    for (int d = 1; d < 512; d <<= 1) {
        unsigned t = (threadIdx.x >= (unsigned)d) ? s[threadIdx.x - d] : 0u;
        __syncthreads();
        s[threadIdx.x] += t;
        __syncthreads();
    }
    if (threadIdx.x < (unsigned)nblk)
        colcnt[(size_t)b * nblk + threadIdx.x] = s[threadIdx.x] - v;
    if (threadIdx.x == 511) btot[b] = s[511];
}

// Phase 2b: scan bucket totals -> bbase[0..nbk], bbase[nbk] = nE.
__global__ __launch_bounds__(512) void k_btots(const unsigned* __restrict__ btot,
                                               unsigned* __restrict__ bbase,
                                               int nbk, int nE) {
    __shared__ unsigned s[512];
    unsigned v = (threadIdx.x < (unsigned)nbk) ? btot[threadIdx.x] : 0u;
    s[threadIdx.x] = v;
    __syncthreads();
    for (int d = 1; d < 512; d <<= 1) {
        unsigned t = (threadIdx.x >= (unsigned)d) ? s[threadIdx.x - d] : 0u;
        __syncthreads();
        s[threadIdx.x] += t;
        __syncthreads();
    }
    if (threadIdx.x < (unsigned)nbk) bbase[threadIdx.x] = s[threadIdx.x] - v;
    if (threadIdx.x == 0) bbase[nbk] = (unsigned)nE;
}

// Phase 3: partition edges into bucket-grouped u32 records.
__global__ __launch_bounds__(256) void k_part(const int* __restrict__ src,
                                              const int* __restrict__ dst,
                                              const unsigned* __restrict__ colcnt,
                                              const unsigned* __restrict__ bbase,
                                              unsigned* __restrict__ ebuf,
                                              int nE, int nbk, int nblk) {
    __shared__ unsigned curs[NBK_MAX];
    int blk = blockIdx.x;
    for (int b = threadIdx.x; b < nbk; b += 256)
        curs[b] = bbase[b] + colcnt[(size_t)b * nblk + blk];
    __syncthreads();
    int e0 = blk * EPB, e1 = min(e0 + EPB, nE);
    for (int e = e0 + threadIdx.x; e < e1; e += 256) {
        int d = dst[e], s = src[e];
        unsigned p = atomicAdd(&curs[d >> 8], 1u);
        ebuf[p] = ((unsigned)(d & 255) << 17) | (unsigned)s;   // src < 2^17
    }
}

// Phase 4: per-bucket fine pass -> offs, dinv, perm.
__global__ __launch_bounds__(256) void k_fine(const unsigned* __restrict__ ebuf,
                                              const unsigned* __restrict__ bbase,
                                              unsigned* __restrict__ offs,
                                              float* __restrict__ dinv,
                                              int* __restrict__ perm, int n) {
    __shared__ unsigned deg[256], pos[256], cur[256];
    int b = blockIdx.x;
    int node0 = b << 8;
    unsigned ebeg = bbase[b], eend = bbase[b + 1];
    deg[threadIdx.x] = 0u;
    __syncthreads();
    for (unsigned e = ebeg + threadIdx.x; e < eend; e += 256)
        atomicAdd(&deg[ebuf[e] >> 17], 1u);
    __syncthreads();
    unsigned v = deg[threadIdx.x];
    pos[threadIdx.x] = v;
    __syncthreads();
    for (int d = 1; d < 256; d <<= 1) {
        unsigned t = (threadIdx.x >= (unsigned)d) ? pos[threadIdx.x - d] : 0u;
        __syncthreads();
        pos[threadIdx.x] += t;
        __syncthreads();
    }
    unsigned excl = pos[threadIdx.x] - v;
    cur[threadIdx.x] = excl;
    int node = node0 + threadIdx.x;
    if (node < n) {
        offs[node] = ebeg + excl;
        dinv[node] = rsqrtf((float)v + 1.0f);    // +1 self-loop
    }
    __syncthreads();
    for (unsigned e = ebeg + threadIdx.x; e < eend; e += 256) {
        unsigned rec = ebuf[e];
        unsigned p = atomicAdd(&cur[rec >> 17], 1u);
        perm[ebeg + p] = (int)(rec & 0x1FFFFu);  // src
    }
}

// ---------------------------------------------------------------------------
// MFMA linear layer (R13-proven): out[r] = dinv[r]*(f(in[r]) @ W), bf16 hi/lo
// split (hh+hl+lh terms ~ f32 precision). 64 rows/block, 4 waves x 16-row
// stripes; W->LDS transposed+padded bf16; mfma_f32_16x16x32_bf16.
// ---------------------------------------------------------------------------
template <int KD, bool RELU>
__global__ __launch_bounds__(256) void k_linm(const float* __restrict__ in,
                                              const float* __restrict__ W,   // [KD][64]
                                              const float* __restrict__ dinv,
                                              unsigned short* __restrict__ outp, int n) {
    constexpr int LDK = KD + 8;
    __shared__ unsigned short WH[64 * LDK];
    __shared__ unsigned short WL[64 * LDK];
    for (int i = threadIdx.x; i < KD * 64; i += 256) {
        int k = i >> 6, c = i & 63;
        float wv = W[i];
        unsigned short h = f2bf(wv);
        WH[c * LDK + k] = h;
        WL[c * LDK + k] = f2bf(wv - bf2f(h));
    }
    __syncthreads();

    int wid = threadIdx.x >> 6, lane = threadIdx.x & 63;
    int r0 = blockIdx.x * 64 + wid * 16;

    constexpr int NK = KD / 32;
    int arow = r0 + (lane & 15);
    int ar = arow < n ? arow : (n - 1);
    int k8 = (lane >> 4) * 8;

    bf16x8 ah[NK], al[NK];
    {
        const float* rp = in + (size_t)ar * KD;
        float dvin = RELU ? dinv[ar] : 0.f;
#pragma unroll
        for (int ks = 0; ks < NK; ++ks) {
            float4 v0 = *(const float4*)(rp + ks * 32 + k8);
            float4 v1 = *(const float4*)(rp + ks * 32 + k8 + 4);
            float xv[8] = {v0.x, v0.y, v0.z, v0.w, v1.x, v1.y, v1.z, v1.w};
#pragma unroll
            for (int j = 0; j < 8; ++j) {
                float f = xv[j];
                if (RELU) f = fmaxf(dvin * f, 0.f);
                unsigned short h = f2bf(f);
                ah[ks][j] = (short)h;
                al[ks][j] = (short)f2bf(f - bf2f(h));
            }
        }
    }

    f32x4 acc[4];
#pragma unroll
    for (int nt = 0; nt < 4; ++nt) {
        int col = nt * 16 + (lane & 15);
        const unsigned short* bh = &WH[col * LDK + k8];
        const unsigned short* bl = &WL[col * LDK + k8];
        f32x4 a = {0.f, 0.f, 0.f, 0.f};
#pragma unroll
        for (int ks = 0; ks < NK; ++ks) {
            bf16x8 Bh = *(const bf16x8*)(bh + ks * 32);
            bf16x8 Bl = *(const bf16x8*)(bl + ks * 32);
            a = __builtin_amdgcn_mfma_f32_16x16x32_bf16(ah[ks], Bh, a, 0, 0, 0);
            a = __builtin_amdgcn_mfma_f32_16x16x32_bf16(ah[ks], Bl, a, 0, 0, 0);
            a = __builtin_amdgcn_mfma_f32_16x16x32_bf16(al[ks], Bh, a, 0, 0, 0);
        }
        acc[nt] = a;
    }

    int orow0 = r0 + (lane >> 4) * 4;
#pragma unroll
    for (int j = 0; j < 4; ++j) {
        int row = orow0 + j;
        if (row < n) {
            float dv = dinv[row];
#pragma unroll
            for (int nt = 0; nt < 4; ++nt)
                outp[(size_t)row * 64 + nt * 16 + (lane & 15)] = f2bf(dv * acc[nt][j]);
        }
    }
}

// ---------------------------------------------------------------------------
// CSR gather, 4-rows-per-load: wave = 4 groups x 16 lanes; group g handles
// edge k+g, lane li reads features li*4..li*4+3 (ushort4, 8B) -> one load
// instruction fetches 4 complete 128B rows. 16-edge unroll (4 acc quads).
// Cross-group combine via shfl_xor(16/32); group 0 stores the 256B row.
// ---------------------------------------------------------------------------
template <bool FIN>
__global__ __launch_bounds__(256) void k_gather(const unsigned short* __restrict__ hs,
                                                const unsigned* __restrict__ offs,
                                                const int* __restrict__ perm,
                                                const float* __restrict__ dinv,
                                                float* __restrict__ outb,
                                                int n, int nE) {
    int lane = threadIdx.x & 63;
    int g = lane >> 4, li = lane & 15;
    int r = blockIdx.x * 4 + (threadIdx.x >> 6);
    if (r >= n) return;
    unsigned beg = offs[r];
    unsigned end = (r + 1 < n) ? offs[r + 1] : (unsigned)nE;

    float4 a0 = {0.f, 0.f, 0.f, 0.f}, a1 = a0, a2 = a0, a3 = a0;
    if (g == 0) {                       // self-loop term (once)
        ushort4 sv = *(const ushort4*)(hs + (size_t)r * 64 + li * 4);
        a0.x = bf2f(sv.x); a0.y = bf2f(sv.y); a0.z = bf2f(sv.z); a0.w = bf2f(sv.w);
    }

    for (unsigned e0 = beg; e0 < end; e0 += 64) {
        unsigned c = min(64u, end - e0);
        int sl = (lane < (int)c) ? perm[e0 + lane] : 0;   // coalesced edge read
        unsigned k = 0;
        for (; k + 16 <= c; k += 16) {                    // 16 edges: 4 loads/lane
            int s0 = __shfl(sl, (int)(k + g));
            int s1 = __shfl(sl, (int)(k + 4 + g));
            int s2 = __shfl(sl, (int)(k + 8 + g));
            int s3 = __shfl(sl, (int)(k + 12 + g));
            ushort4 v0 = *(const ushort4*)(hs + (size_t)s0 * 64 + li * 4);
            ushort4 v1 = *(const ushort4*)(hs + (size_t)s1 * 64 + li * 4);
            ushort4 v2 = *(const ushort4*)(hs + (size_t)s2 * 64 + li * 4);
            ushort4 v3 = *(const ushort4*)(hs + (size_t)s3 * 64 + li * 4);
            a0.x += bf2f(v0.x); a0.y += bf2f(v0.y); a0.z += bf2f(v0.z); a0.w += bf2f(v0.w);
            a1.x += bf2f(v1.x); a1.y += bf2f(v1.y); a1.z += bf2f(v1.z); a1.w += bf2f(v1.w);
            a2.x += bf2f(v2.x); a2.y += bf2f(v2.y); a2.z += bf2f(v2.z); a2.w += bf2f(v2.w);
            a3.x += bf2f(v3.x); a3.y += bf2f(v3.y); a3.z += bf2f(v3.z); a3.w += bf2f(v3.w);
        }
        for (; k < c; k += 4) {                           // 4-edge tail, predicated
            int idx = (int)k + g;
            bool val = idx < (int)c;
            int s = __shfl(sl, val ? idx : 0);
            ushort4 v = *(const ushort4*)(hs + (size_t)s * 64 + li * 4);
            if (val) {
                a0.x += bf2f(v.x); a0.y += bf2f(v.y);
                a0.z += bf2f(v.z); a0.w += bf2f(v.w);
            }
        }
    }

    float4 acc;
    acc.x = (a0.x + a1.x) + (a2.x + a3.x);
    acc.y = (a0.y + a1.y) + (a2.y + a3.y);
    acc.z = (a0.z + a1.z) + (a2.z + a3.z);
    acc.w = (a0.w + a1.w) + (a2.w + a3.w);
    // combine the 4 lane-groups (bits 4,5 of lane)
    acc.x += __shfl_xor(acc.x, 16); acc.x += __shfl_xor(acc.x, 32);
    acc.y += __shfl_xor(acc.y, 16); acc.y += __shfl_xor(acc.y, 32);
    acc.z += __shfl_xor(acc.z, 16); acc.z += __shfl_xor(acc.z, 32);
    acc.w += __shfl_xor(acc.w, 16); acc.w += __shfl_xor(acc.w, 32);

    if (g == 0) {
        if (FIN) {
            float dv = dinv[r];
            acc.x *= dv; acc.y *= dv; acc.z *= dv; acc.w *= dv;
        }
        *(float4*)(outb + (size_t)r * 64 + li * 4) = acc;   // 16 lanes x 16B = 256B row
    }
}

// ---------------------------------------------------------------------------
extern "C" void kernel_launch(void* const* d_in, const int* in_sizes, int n_in,
                              void* d_out, int out_size, void* d_ws, size_t ws_size,
                              hipStream_t stream) {
    const float* x  = (const float*)d_in[0];
    const int*   ei = (const int*)d_in[1];
    const float* W1 = (const float*)d_in[2];
    const float* W2 = (const float*)d_in[3];
    float* out = (float*)d_out;

    int n  = in_sizes[0] / IN_DIM;   // 100000
    int nE = in_sizes[1] / 2;        // 1600000
    const int* src = ei;
    const int* dst = ei + nE;

    int nbk  = (n + 255) >> 8;               // coarse buckets (391)
    int nblk = (nE + EPB - 1) / EPB;         // count/partition blocks (391)

    // workspace carve-up (256B-aligned); d_out doubles as the layer-1 agg buffer
    char* w = (char*)d_ws;
    size_t nAl = ((size_t)n * 4 + 255) & ~(size_t)255;
    float*          dinv   = (float*)w;     w += nAl;
    unsigned*       offs   = (unsigned*)w;  w += nAl;
    unsigned*       colcnt = (unsigned*)w;  w += ((size_t)nbk * nblk * 4 + 255) & ~(size_t)255;
    unsigned*       btot   = (unsigned*)w;  w += ((size_t)nbk * 4 + 255) & ~(size_t)255;
    unsigned*       bbase  = (unsigned*)w;  w += ((size_t)(nbk + 1) * 4 + 255) & ~(size_t)255;
    unsigned*       ebuf   = (unsigned*)w;  w += ((size_t)nE * 4 + 255) & ~(size_t)255;
    int*            perm   = (int*)w;       w += ((size_t)nE * 4 + 255) & ~(size_t)255;
    unsigned short* hs     = (unsigned short*)w; w += (size_t)n * 64 * 2;
    float*          agg    = out;            // layer-1 aggregate lives in d_out

    int gRow = (n + 3) / 4;
    int gMf  = (n + 63) / 64;

    // --- CSR build: two-level LDS counting sort ---
    k_cnt  <<<nblk, 256, 0, stream>>>(dst, colcnt, nE, nbk, nblk);
    k_bsum <<<nbk,  512, 0, stream>>>(colcnt, btot, nbk, nblk);
    k_btots<<<1,    512, 0, stream>>>(btot, bbase, nbk, nE);
    k_part <<<nblk, 256, 0, stream>>>(src, dst, colcnt, bbase, ebuf, nE, nbk, nblk);
    k_fine <<<nbk,  256, 0, stream>>>(ebuf, bbase, offs, dinv, perm, n);

    // --- layer 1 ---
    k_linm<IN_DIM, false><<<gMf, 256, 0, stream>>>(x, W1, dinv, hs, n);
    k_gather<false><<<gRow, 256, 0, stream>>>(hs, offs, perm, dinv, agg, n, nE);

    // --- layer 2 (reuse hs; final dinv folded into gather) ---
    k_linm<OUT_DIM, true><<<gMf, 256, 0, stream>>>(agg, W2, dinv, hs, n);
    k_gather<true><<<gRow, 256, 0, stream>>>(hs, offs, perm, dinv, out, n, nE);
}